// Round 9
// baseline (1271.727 us; speedup 1.0000x reference)
//
#include <hip/hip_runtime.h>
#include <hip/hip_bf16.h>

#define T_TOK 2048
#define H_DIM 1024
#define E_EXP 32
#define F_DIM 512
#define FS_DIM 1024
#define K_TOP 8
#define NGRP 8
#define TGRP 4
#define GSZ (E_EXP / NGRP)
#define RSCALE 2.5f
#define CAP 2048

typedef short  short8 __attribute__((ext_vector_type(8)));
typedef __bf16 bf16x8 __attribute__((ext_vector_type(8)));
typedef float  f32x4  __attribute__((ext_vector_type(4)));

// ---------------- routing + x->bf16 (fp32 selection, exact reference semantics) ----------------
// NO atomics here (round-5 lesson: 8 dependent atomicAdd per wave serialized -> 165 us).
__global__ __launch_bounds__(64) void route_kernel(
    const float* __restrict__ x, const float* __restrict__ gw,
    const float* __restrict__ bias, int* __restrict__ tk_idx,
    float* __restrict__ tk_w, __bf16* __restrict__ xb) {
  const int t = blockIdx.x;
  const int lane = threadIdx.x;
  float xr[16];
#pragma unroll
  for (int i = 0; i < 16; i++) xr[i] = x[t * H_DIM + i * 64 + lane];
#pragma unroll
  for (int i = 0; i < 16; i++) xb[t * H_DIM + i * 64 + lane] = (__bf16)xr[i];
  float sc[E_EXP];
#pragma unroll
  for (int e = 0; e < E_EXP; e++) {
    const float* w = gw + e * H_DIM;
    float s = 0.f;
#pragma unroll
    for (int i = 0; i < 16; i++) s += xr[i] * w[i * 64 + lane];
#pragma unroll
    for (int off = 32; off > 0; off >>= 1) s += __shfl_xor(s, off);
    sc[e] = 1.f / (1.f + expf(-s));
  }
  if (lane == 0) {
    float b[E_EXP];
    for (int e = 0; e < E_EXP; e++) b[e] = sc[e] + bias[e];
    float gs[NGRP];
    for (int g = 0; g < NGRP; g++) {
      float m1 = -1e30f, m2 = -1e30f;
      for (int j = 0; j < GSZ; j++) {
        float v = b[g * GSZ + j];
        if (v > m1) { m2 = m1; m1 = v; } else if (v > m2) { m2 = v; }
      }
      gs[g] = m1 + m2;
    }
    unsigned gmask = 0;
    for (int it = 0; it < TGRP; it++) {
      float best = -1e30f; int bi = 0;
      for (int g = 0; g < NGRP; g++)
        if (!((gmask >> g) & 1) && gs[g] > best) { best = gs[g]; bi = g; }
      gmask |= 1u << bi;
    }
    unsigned emask = 0; float wsum = 0.f;
    int idx8[K_TOP];
    for (int it = 0; it < K_TOP; it++) {
      float best = -1e30f; int bi = 0;
      for (int e = 0; e < E_EXP; e++) {
        if (!((gmask >> (e / GSZ)) & 1)) continue;
        if ((emask >> e) & 1) continue;
        if (b[e] > best) { best = b[e]; bi = e; }
      }
      emask |= 1u << bi;
      idx8[it] = bi;
      wsum += sc[bi];
    }
    const float inv = 1.f / (wsum + 1e-20f);
    for (int k = 0; k < K_TOP; k++) {
      tk_idx[t * K_TOP + k] = idx8[k];
      tk_w[t * K_TOP + k] = sc[idx8[k]] * inv;
    }
  }
}

// ---------------- scatter: wave-parallel per-lane atomics ----------------
__global__ void scatter_kernel(const int* __restrict__ tk_idx, int* __restrict__ counts,
                               int* __restrict__ recs) {
  const int i = blockIdx.x * blockDim.x + threadIdx.x;
  if (i >= T_TOK * K_TOP) return;
  const int e = tk_idx[i];
  const int pos = atomicAdd(&counts[e], 1);
  recs[e * CAP + pos] = i;  // i == t*8 + k
}

// ---------------- fused grouped+shared GEMM: bf16 A x fp32 B (direct weight read) ----------------
// R6-proven single-buffered m97 loop; B staged as raw fp32 via async global_load_lds
// (16B chunks are dtype-agnostic), converted to bf16 at fragment-read time (clang
// fuses scalar casts to v_cvt_pk_bf16_f32). Eliminates the separate 306-MB cvt pass.
#define BM 128
#define BN 128
#define BK 64

__device__ __forceinline__ void gload_lds16(const void* g, void* l) {
  __builtin_amdgcn_global_load_lds(
      (__attribute__((address_space(1))) const void*)g,
      (__attribute__((address_space(3))) void*)l, 16, 0, 0);
}

// PHASE 0: z<32 -> GU expert z (A=xb gather, B=wgu fp32, out=h_buf bf16 silu*up)
//          z in {32,33} -> shared GU slice s=z-32 (A=xb dense, B=sgu fp32, out=hs)
// PHASE 1: z<32 -> DOWN expert z (A=h_buf slab, B=wd fp32, out=y_slot fp32 * tk_w)
//          z==32 -> shared DOWN (A=hs dense, B=sd fp32, out=d_out fp32)
template <int PHASE>
__global__ __launch_bounds__(256) void gemm_fused(
    const __bf16* __restrict__ Ar, const __bf16* __restrict__ As_,
    const float* __restrict__ Br, const float* __restrict__ Bs_,
    void* __restrict__ OutR, void* __restrict__ OutS,
    const int* __restrict__ recs, const int* __restrict__ counts,
    const float* __restrict__ tk_w) {

  const int z = blockIdx.z;
  const bool routed = (z < E_EXP);
  const int e = z;
  const int m0 = blockIdx.y * BM;
  const int bx = blockIdx.x;

  int count = T_TOK, off_e = 0;
  if (routed) {
    count = counts[e];
    for (int i = 0; i < E_EXP; i++) off_e += (i < e) ? counts[i] : 0;
    if (m0 >= count) return;   // block-uniform early exit, before any barrier
  }
  const int K = (PHASE == 0) ? H_DIM : (routed ? F_DIM : FS_DIM);

  const int tid = threadIdx.x, wid = tid >> 6, lane = tid & 63;

  __shared__ __align__(16) __bf16 Atile[BM * BK];   // 16 KB
  __shared__ __align__(16) float  Btile[BN * BK];   // 32 KB  (48 KB total)

  // ---- A source pointers (bf16, 4 x 16B per lane) ----
  const int colk = (lane & 7) * 8;
  const __bf16* aptr[4];
#pragma unroll
  for (int i = 0; i < 4; i++) {
    const int row = wid * 32 + i * 8 + (lane >> 3);
    int r = m0 + row; if (r > count - 1) r = count - 1;
    if (PHASE == 0) {
      if (routed) {
        const int rec = recs[e * CAP + r];
        aptr[i] = Ar + (size_t)(rec >> 3) * H_DIM + colk;     // gather token row of xb
      } else {
        aptr[i] = As_ + (size_t)r * H_DIM + colk;             // dense xb
      }
    } else {
      if (routed) aptr[i] = Ar + (size_t)(off_e + r) * F_DIM + colk;   // h slab
      else        aptr[i] = As_ + (size_t)r * FS_DIM + colk;           // hs dense
    }
  }

  // ---- B source: fp32, 8 x 16B (4 floats) per lane per tile ----
  // LDS row r gets global B row brow(r); lane covers col floats (lane&15)*4,
  // rows wid*32 + i*4 + (lane>>4)  (implicit lane*16B dest offset matches).
  const float* bbase = (PHASE == 0)
      ? (routed ? Br + (size_t)e * 2 * F_DIM * H_DIM : Bs_)
      : (routed ? Br + (size_t)e * H_DIM * F_DIM : Bs_);
  unsigned boff[8];
#pragma unroll
  for (int i = 0; i < 8; i++) {
    const int row = wid * 32 + i * 4 + (lane >> 4);
    int brow;
    if (PHASE == 0) {
      if (routed) {
        brow = (row < 64) ? (bx * 64 + row) : (F_DIM + bx * 64 + row - 64);
      } else {
        const int s = z - E_EXP;
        const int fglob = s * 512 + bx * 64 + (row & 63);
        brow = (row < 64) ? fglob : (FS_DIM + fglob);
      }
    } else {
      brow = bx * BN + row;
    }
    boff[i] = (unsigned)(brow * K + (lane & 15) * 4);
  }

  auto STAGE = [&](int k0) {
#pragma unroll
    for (int i = 0; i < 4; i++)
      gload_lds16(aptr[i] + k0, (char*)Atile + (wid * 4 + i) * 1024);
#pragma unroll
    for (int i = 0; i < 8; i++)
      gload_lds16(bbase + boff[i] + k0, (char*)Btile + (wid * 32 + i * 4) * 256);
  };

  f32x4 acc[2][8];
#pragma unroll
  for (int a = 0; a < 2; a++)
#pragma unroll
    for (int b = 0; b < 8; b++) acc[a][b] = f32x4{0.f, 0.f, 0.f, 0.f};

  const int lr = lane & 15, lh = lane >> 4;

  for (int k0 = 0; k0 < K; k0 += BK) {
    STAGE(k0);
    __syncthreads();
#pragma unroll
    for (int kk = 0; kk < 2; kk++) {
      short8 af[2], bfr[8];
#pragma unroll
      for (int fm = 0; fm < 2; fm++)
        af[fm] = *reinterpret_cast<const short8*>(&Atile[(wid * 32 + fm * 16 + lr) * BK + kk * 32 + lh * 8]);
#pragma unroll
      for (int fn = 0; fn < 8; fn++) {
        const float4 lo = *reinterpret_cast<const float4*>(&Btile[(fn * 16 + lr) * BK + kk * 32 + lh * 8]);
        const float4 hi = *reinterpret_cast<const float4*>(&Btile[(fn * 16 + lr) * BK + kk * 32 + lh * 8 + 4]);
        bf16x8 bv;
        bv[0] = (__bf16)lo.x; bv[1] = (__bf16)lo.y; bv[2] = (__bf16)lo.z; bv[3] = (__bf16)lo.w;
        bv[4] = (__bf16)hi.x; bv[5] = (__bf16)hi.y; bv[6] = (__bf16)hi.z; bv[7] = (__bf16)hi.w;
        bfr[fn] = *reinterpret_cast<short8*>(&bv);
      }
#pragma unroll
      for (int fn = 0; fn < 8; fn++)
#pragma unroll
        for (int fm = 0; fm < 2; fm++)
          acc[fm][fn] = __builtin_amdgcn_mfma_f32_16x16x32_bf16(af[fm], bfr[fn], acc[fm][fn], 0, 0, 0);
    }
    __syncthreads();
  }

  // ---------------- epilogues ----------------
  if (PHASE == 0) {
    // silu(gate) * up -> bf16
#pragma unroll
    for (int fm = 0; fm < 2; fm++)
#pragma unroll
      for (int j = 0; j < 4; j++) {
        const int row = wid * 32 + fm * 16 + lh * 4 + j;
        if (m0 + row < count) {
#pragma unroll
          for (int fn = 0; fn < 4; fn++) {
            const float g = acc[fm][fn][j], u = acc[fm][fn + 4][j];
            const float hv = g / (1.f + expf(-g)) * u;
            if (routed) {
              const int f = bx * 64 + fn * 16 + lr;
              ((__bf16*)OutR)[(size_t)(off_e + m0 + row) * F_DIM + f] = (__bf16)hv;
            } else {
              const int s = z - E_EXP;
              const int f = s * 512 + bx * 64 + fn * 16 + lr;
              ((__bf16*)OutS)[(size_t)(m0 + row) * FS_DIM + f] = (__bf16)hv;
            }
          }
        }
      }
  } else {
#pragma unroll
    for (int fm = 0; fm < 2; fm++)
#pragma unroll
      for (int j = 0; j < 4; j++) {
        const int row = wid * 32 + fm * 16 + lh * 4 + j;
        if (m0 + row < count) {
          if (routed) {
            const int rec = recs[e * CAP + m0 + row];   // == t*8+k, the y_slot row
            const float w = tk_w[rec];
            const size_t base = (size_t)rec * H_DIM + bx * BN;
#pragma unroll
            for (int fn = 0; fn < 8; fn++)
              ((float*)OutR)[base + fn * 16 + lr] = acc[fm][fn][j] * w;
          } else {
#pragma unroll
            for (int fn = 0; fn < 8; fn++)
              ((float*)OutS)[(size_t)(m0 + row) * H_DIM + bx * BN + fn * 16 + lr] = acc[fm][fn][j];
          }
        }
      }
  }
}

// ---------------- combine: out = shared + SCALE * sum_k y_slot[t,k] ----------------
__global__ void combine_kernel(const float* __restrict__ y_slot, float* __restrict__ out) {
  const int gid = blockIdx.x * blockDim.x + threadIdx.x;
  const int t = gid >> 8;
  const int c0 = (gid & 255) * 4;
  float4 s = {0.f, 0.f, 0.f, 0.f};
#pragma unroll
  for (int k = 0; k < K_TOP; k++) {
    const float4 v = *reinterpret_cast<const float4*>(&y_slot[((size_t)t * K_TOP + k) * H_DIM + c0]);
    s.x += v.x; s.y += v.y; s.z += v.z; s.w += v.w;
  }
  float4 o = *reinterpret_cast<float4*>(&out[(size_t)t * H_DIM + c0]);
  o.x += RSCALE * s.x; o.y += RSCALE * s.y; o.z += RSCALE * s.z; o.w += RSCALE * s.w;
  *reinterpret_cast<float4*>(&out[(size_t)t * H_DIM + c0]) = o;
}

// ---------------- launch ----------------
extern "C" void kernel_launch(void* const* d_in, const int* in_sizes, int n_in,
                              void* d_out, int out_size, void* d_ws, size_t ws_size,
                              hipStream_t stream) {
  const float* x    = (const float*)d_in[0];
  const float* gw   = (const float*)d_in[1];
  const float* bias = (const float*)d_in[2];
  const float* wgu  = (const float*)d_in[3];
  const float* wd   = (const float*)d_in[4];
  const float* sgu  = (const float*)d_in[5];
  const float* sd   = (const float*)d_in[6];

  char* ws = (char*)d_ws;
  size_t o = 0;
  auto alloc = [&](size_t bytes) {
    char* p = ws + o;
    o += (bytes + 255) & ~(size_t)255;
    return (void*)p;
  };
  __bf16* xb     = (__bf16*)alloc((size_t)T_TOK * H_DIM * 2);
  __bf16* h_buf  = (__bf16*)alloc((size_t)T_TOK * K_TOP * F_DIM * 2);
  float*  y_slot = (float*) alloc((size_t)T_TOK * K_TOP * H_DIM * 4);
  __bf16* hs     = (__bf16*)alloc((size_t)T_TOK * FS_DIM * 2);
  int*   tk_idx  = (int*)  alloc((size_t)T_TOK * K_TOP * 4);
  float* tk_w    = (float*)alloc((size_t)T_TOK * K_TOP * 4);
  int*   counts  = (int*)  alloc((size_t)E_EXP * 4);
  int*   recs    = (int*)  alloc((size_t)E_EXP * CAP * 4);
  if (o > ws_size) return;

  // 1. routing + x conversion (no atomics)
  route_kernel<<<T_TOK, 64, 0, stream>>>(x, gw, bias, tk_idx, tk_w, xb);

  // 2. scatter (wave-parallel atomics)
  hipMemsetAsync(counts, 0, E_EXP * 4, stream);
  scatter_kernel<<<(T_TOK * K_TOP + 255) / 256, 256, 0, stream>>>(tk_idx, counts, recs);

  // 3. gate_up (routed z<32, shared slices z=32,33) — B read directly from fp32 weights
  gemm_fused<0><<<dim3(F_DIM / 64, T_TOK / BM, E_EXP + 2), 256, 0, stream>>>(
      xb, xb, wgu, sgu, h_buf, hs, recs, counts, tk_w);

  // 4. down (routed z<32, shared z=32)
  gemm_fused<1><<<dim3(H_DIM / BN, T_TOK / BM, E_EXP + 1), 256, 0, stream>>>(
      h_buf, hs, wd, sd, y_slot, d_out, recs, counts, tk_w);

  // 5. combine
  combine_kernel<<<T_TOK * H_DIM / 4 / 256, 256, 0, stream>>>(y_slot, (float*)d_out);
}

// Round 10
// 332.001 us; speedup vs baseline: 3.8305x; 3.8305x over previous
//
#include <hip/hip_runtime.h>
#include <hip/hip_bf16.h>

#define T_TOK 2048
#define H_DIM 1024
#define E_EXP 32
#define F_DIM 512
#define FS_DIM 1024
#define K_TOP 8
#define NGRP 8
#define TGRP 4
#define GSZ (E_EXP / NGRP)
#define RSCALE 2.5f
#define CAP 2048

typedef short  short8 __attribute__((ext_vector_type(8)));
typedef __bf16 bf16x4 __attribute__((ext_vector_type(4)));
typedef float  f32x4  __attribute__((ext_vector_type(4)));

// ---- one float4 -> bf16x4 conversion over a split (s0,n0)+(s1,...) range ----
__device__ __forceinline__ void cvt4_split(const float* __restrict__ s0, __bf16* __restrict__ d0, int n0,
                                           const float* __restrict__ s1, __bf16* __restrict__ d1, int j) {
  const float* src = (j < n0) ? s0 : s1;
  __bf16* dst = (j < n0) ? d0 : d1;
  const int i = (j < n0) ? j : (j - n0);
  const float4 v = reinterpret_cast<const float4*>(src)[i];
  bf16x4 o;
  o[0] = (__bf16)v.x; o[1] = (__bf16)v.y; o[2] = (__bf16)v.z; o[3] = (__bf16)v.w;
  reinterpret_cast<bf16x4*>(dst)[i] = o;
}

// ================ prep: route (blocks 0..511, wave-per-token) ∥ cvt wgu+sgu ================
// route and the gate_up weight conversion are data-independent; fusing hides route's
// 18 us latency-bound tail inside the HBM-bound conversion. NO atomics in route
// (round-5 lesson: dependent per-wave atomicAdd serialized -> 165 us).
#define NROUTE_BLK (T_TOK / 4)
__global__ __launch_bounds__(256) void prep_kernel(
    const float* __restrict__ x, const float* __restrict__ gw,
    const float* __restrict__ bias, int* __restrict__ tk_idx,
    float* __restrict__ tk_w, __bf16* __restrict__ xb,
    const float* __restrict__ wgu, __bf16* __restrict__ wgub,
    const float* __restrict__ sgu, __bf16* __restrict__ sgub) {
  if (blockIdx.x < NROUTE_BLK) {
    const int wid = threadIdx.x >> 6, lane = threadIdx.x & 63;
    const int t = blockIdx.x * 4 + wid;
    float xr[16];
#pragma unroll
    for (int i = 0; i < 16; i++) xr[i] = x[t * H_DIM + i * 64 + lane];
#pragma unroll
    for (int i = 0; i < 16; i++) xb[t * H_DIM + i * 64 + lane] = (__bf16)xr[i];
    float sc[E_EXP];
#pragma unroll
    for (int e = 0; e < E_EXP; e++) {
      const float* w = gw + e * H_DIM;
      float s = 0.f;
#pragma unroll
      for (int i = 0; i < 16; i++) s += xr[i] * w[i * 64 + lane];
#pragma unroll
      for (int off = 32; off > 0; off >>= 1) s += __shfl_xor(s, off);
      sc[e] = 1.f / (1.f + expf(-s));
    }
    if (lane == 0) {
      float b[E_EXP];
      for (int e = 0; e < E_EXP; e++) b[e] = sc[e] + bias[e];
      float gs[NGRP];
      for (int g = 0; g < NGRP; g++) {
        float m1 = -1e30f, m2 = -1e30f;
        for (int j = 0; j < GSZ; j++) {
          float v = b[g * GSZ + j];
          if (v > m1) { m2 = m1; m1 = v; } else if (v > m2) { m2 = v; }
        }
        gs[g] = m1 + m2;
      }
      unsigned gmask = 0;
      for (int it = 0; it < TGRP; it++) {
        float best = -1e30f; int bi = 0;
        for (int g = 0; g < NGRP; g++)
          if (!((gmask >> g) & 1) && gs[g] > best) { best = gs[g]; bi = g; }
        gmask |= 1u << bi;
      }
      unsigned emask = 0; float wsum = 0.f;
      int idx8[K_TOP];
      for (int it = 0; it < K_TOP; it++) {
        float best = -1e30f; int bi = 0;
        for (int e = 0; e < E_EXP; e++) {
          if (!((gmask >> (e / GSZ)) & 1)) continue;
          if ((emask >> e) & 1) continue;
          if (b[e] > best) { best = b[e]; bi = e; }
        }
        emask |= 1u << bi;
        idx8[it] = bi;
        wsum += sc[bi];
      }
      const float inv = 1.f / (wsum + 1e-20f);
      for (int k = 0; k < K_TOP; k++) {
        tk_idx[t * K_TOP + k] = idx8[k];
        tk_w[t * K_TOP + k] = sc[idx8[k]] * inv;
      }
    }
  } else {
    // cvt wgu (64MB bf16) + sgu (4MB bf16), 4-deep batched grid-stride
    const int n0 = E_EXP * 2 * F_DIM * H_DIM / 4;
    const int n1 = 2 * FS_DIM * H_DIM / 4;
    const int ntot = n0 + n1;
    const int nthr = (gridDim.x - NROUTE_BLK) * 256;
    const int base = (blockIdx.x - NROUTE_BLK) * 256 + threadIdx.x;
    for (int i = base; i < ntot; i += 4 * nthr) {
#pragma unroll
      for (int u = 0; u < 4; u++) {
        const int j = i + u * nthr;
        if (j < ntot) cvt4_split(wgu, wgub, n0, sgu, sgub, j);
      }
    }
  }
}

// ---------------- scatter: wave-parallel per-lane atomics ----------------
__global__ void scatter_kernel(const int* __restrict__ tk_idx, int* __restrict__ counts,
                               int* __restrict__ recs) {
  const int i = blockIdx.x * blockDim.x + threadIdx.x;
  if (i >= T_TOK * K_TOP) return;
  const int e = tk_idx[i];
  const int pos = atomicAdd(&counts[e], 1);
  recs[e * CAP + pos] = i;  // i == t*8 + k
}

// ---------------- fused grouped+shared GEMM (R6-proven m97 structure, 128x128, BK=64) ----------------
#define BM 128
#define BN 128
#define BK 64

__device__ __forceinline__ void gload_lds16(const void* g, void* l) {
  __builtin_amdgcn_global_load_lds(
      (__attribute__((address_space(1))) const void*)g,
      (__attribute__((address_space(3))) void*)l, 16, 0, 0);
}

// PHASE 0: z<32 -> GU expert z (A=xb gather, B=wgub, out=h_buf bf16 silu*up)
//          z in {32,33} -> shared GU slice s=z-32 (A=xb dense, B=sgub, out=hs)
//          z==34 -> cvt slice: convert wd+sd fp32->bf16 (gemm<1> input; dispatch
//                   boundary is the fence; hides ~107MB of HBM work under GU compute)
// PHASE 1: z<32 -> DOWN expert z (A=h_buf slab, B=wdb, out=y_slot fp32 * tk_w)
//          z==32 -> shared DOWN (A=hs dense, B=sdb, out=d_out fp32)
template <int PHASE>
__global__ __launch_bounds__(256) void gemm_fused(
    const __bf16* __restrict__ Ar, const __bf16* __restrict__ As_,
    const __bf16* __restrict__ Br, const __bf16* __restrict__ Bs_,
    void* __restrict__ OutR, void* __restrict__ OutS,
    const int* __restrict__ recs, const int* __restrict__ counts,
    const float* __restrict__ tk_w,
    const float* __restrict__ cvt_s0, __bf16* __restrict__ cvt_d0,
    const float* __restrict__ cvt_s1, __bf16* __restrict__ cvt_d1) {

  const int z = blockIdx.z;

  if (PHASE == 0 && z == E_EXP + 2) {
    // conversion slice: 128 blocks grid-stride wd (n0) + sd (n1)
    const int n0 = E_EXP * H_DIM * F_DIM / 4;
    const int n1 = H_DIM * FS_DIM / 4;
    const int ntot = n0 + n1;
    const int nthr = gridDim.x * gridDim.y * 256;
    const int base = (blockIdx.y * gridDim.x + blockIdx.x) * 256 + threadIdx.x;
    for (int i = base; i < ntot; i += 4 * nthr) {
#pragma unroll
      for (int u = 0; u < 4; u++) {
        const int j = i + u * nthr;
        if (j < ntot) cvt4_split(cvt_s0, cvt_d0, n0, cvt_s1, cvt_d1, j);
      }
    }
    return;
  }

  const bool routed = (z < E_EXP);
  const int e = z;
  const int m0 = blockIdx.y * BM;
  const int bx = blockIdx.x;

  int count = T_TOK, off_e = 0;
  if (routed) {
    count = counts[e];
    for (int i = 0; i < E_EXP; i++) off_e += (i < e) ? counts[i] : 0;
    if (m0 >= count) return;   // block-uniform early exit, before any barrier
  }
  const int K = (PHASE == 0) ? H_DIM : (routed ? F_DIM : FS_DIM);

  const int tid = threadIdx.x, wid = tid >> 6, lane = tid & 63;

  __shared__ __align__(16) __bf16 Atile[BM * BK];
  __shared__ __align__(16) __bf16 Btile[BN * BK];

  const int colk = (lane & 7) * 8;
  const __bf16* aptr[4];
  const __bf16* bptr[4];
#pragma unroll
  for (int i = 0; i < 4; i++) {
    const int row = wid * 32 + i * 8 + (lane >> 3);
    int r = m0 + row; if (r > count - 1) r = count - 1;
    // ---- A source ----
    if (PHASE == 0) {
      if (routed) {
        const int rec = recs[e * CAP + r];
        aptr[i] = Ar + (size_t)(rec >> 3) * H_DIM + colk;     // gather token row of xb
      } else {
        aptr[i] = As_ + (size_t)r * H_DIM + colk;             // dense xb
      }
    } else {
      if (routed) aptr[i] = Ar + (size_t)(off_e + r) * F_DIM + colk;   // h slab
      else        aptr[i] = As_ + (size_t)r * FS_DIM + colk;           // hs dense
    }
    // ---- B source ----
    if (PHASE == 0) {
      if (routed) {
        const int brow = (row < 64) ? (bx * 64 + row) : (F_DIM + bx * 64 + row - 64);
        bptr[i] = Br + (size_t)e * 2 * F_DIM * H_DIM + (size_t)brow * H_DIM + colk;
      } else {
        const int s = z - E_EXP;
        const int fglob = s * 512 + bx * 64 + (row & 63);
        const int brow = (row < 64) ? fglob : (FS_DIM + fglob);
        bptr[i] = Bs_ + (size_t)brow * H_DIM + colk;
      }
    } else {
      if (routed) {
        const int brow = bx * BN + row;
        bptr[i] = Br + (size_t)e * H_DIM * F_DIM + (size_t)brow * F_DIM + colk;
      } else {
        const int brow = bx * BN + row;
        bptr[i] = Bs_ + (size_t)brow * FS_DIM + colk;
      }
    }
  }

  f32x4 acc[2][8];
#pragma unroll
  for (int a = 0; a < 2; a++)
#pragma unroll
    for (int b = 0; b < 8; b++) acc[a][b] = f32x4{0.f, 0.f, 0.f, 0.f};

  const int lr = lane & 15, lh = lane >> 4;

  for (int k0 = 0; k0 < K; k0 += BK) {
#pragma unroll
    for (int i = 0; i < 4; i++)
      gload_lds16(aptr[i] + k0, (char*)Atile + (wid * 4 + i) * 1024);
#pragma unroll
    for (int i = 0; i < 4; i++)
      gload_lds16(bptr[i] + k0, (char*)Btile + (wid * 4 + i) * 1024);
    __syncthreads();
#pragma unroll
    for (int kk = 0; kk < 2; kk++) {
      short8 af[2], bfr[8];
#pragma unroll
      for (int fm = 0; fm < 2; fm++)
        af[fm] = *reinterpret_cast<const short8*>(&Atile[(wid * 32 + fm * 16 + lr) * BK + kk * 32 + lh * 8]);
#pragma unroll
      for (int fn = 0; fn < 8; fn++)
        bfr[fn] = *reinterpret_cast<const short8*>(&Btile[(fn * 16 + lr) * BK + kk * 32 + lh * 8]);
#pragma unroll
      for (int fn = 0; fn < 8; fn++)
#pragma unroll
        for (int fm = 0; fm < 2; fm++)
          acc[fm][fn] = __builtin_amdgcn_mfma_f32_16x16x32_bf16(af[fm], bfr[fn], acc[fm][fn], 0, 0, 0);
    }
    __syncthreads();
  }

  // ---------------- epilogues ----------------
  if (PHASE == 0) {
    // silu(gate) * up -> bf16
#pragma unroll
    for (int fm = 0; fm < 2; fm++)
#pragma unroll
      for (int j = 0; j < 4; j++) {
        const int row = wid * 32 + fm * 16 + lh * 4 + j;
        if (m0 + row < count) {
#pragma unroll
          for (int fn = 0; fn < 4; fn++) {
            const float g = acc[fm][fn][j], u = acc[fm][fn + 4][j];
            const float hv = g / (1.f + expf(-g)) * u;
            if (routed) {
              const int f = bx * 64 + fn * 16 + lr;
              ((__bf16*)OutR)[(size_t)(off_e + m0 + row) * F_DIM + f] = (__bf16)hv;
            } else {
              const int s = z - E_EXP;
              const int f = s * 512 + bx * 64 + fn * 16 + lr;
              ((__bf16*)OutS)[(size_t)(m0 + row) * FS_DIM + f] = (__bf16)hv;
            }
          }
        }
      }
  } else {
#pragma unroll
    for (int fm = 0; fm < 2; fm++)
#pragma unroll
      for (int j = 0; j < 4; j++) {
        const int row = wid * 32 + fm * 16 + lh * 4 + j;
        if (m0 + row < count) {
          if (routed) {
            const int rec = recs[e * CAP + m0 + row];   // == t*8+k, the y_slot row
            const float w = tk_w[rec];
            const size_t base = (size_t)rec * H_DIM + bx * BN;
#pragma unroll
            for (int fn = 0; fn < 8; fn++)
              ((float*)OutR)[base + fn * 16 + lr] = acc[fm][fn][j] * w;
          } else {
#pragma unroll
            for (int fn = 0; fn < 8; fn++)
              ((float*)OutS)[(size_t)(m0 + row) * H_DIM + bx * BN + fn * 16 + lr] = acc[fm][fn][j];
          }
        }
      }
  }
}

// ---------------- combine: out = shared + SCALE * sum_k y_slot[t,k] ----------------
__global__ void combine_kernel(const float* __restrict__ y_slot, float* __restrict__ out) {
  const int gid = blockIdx.x * blockDim.x + threadIdx.x;
  const int t = gid >> 8;
  const int c0 = (gid & 255) * 4;
  float4 s = {0.f, 0.f, 0.f, 0.f};
#pragma unroll
  for (int k = 0; k < K_TOP; k++) {
    const float4 v = *reinterpret_cast<const float4*>(&y_slot[((size_t)t * K_TOP + k) * H_DIM + c0]);
    s.x += v.x; s.y += v.y; s.z += v.z; s.w += v.w;
  }
  float4 o = *reinterpret_cast<float4*>(&out[(size_t)t * H_DIM + c0]);
  o.x += RSCALE * s.x; o.y += RSCALE * s.y; o.z += RSCALE * s.z; o.w += RSCALE * s.w;
  *reinterpret_cast<float4*>(&out[(size_t)t * H_DIM + c0]) = o;
}

// ---------------- launch ----------------
extern "C" void kernel_launch(void* const* d_in, const int* in_sizes, int n_in,
                              void* d_out, int out_size, void* d_ws, size_t ws_size,
                              hipStream_t stream) {
  const float* x    = (const float*)d_in[0];
  const float* gw   = (const float*)d_in[1];
  const float* bias = (const float*)d_in[2];
  const float* wgu  = (const float*)d_in[3];
  const float* wd   = (const float*)d_in[4];
  const float* sgu  = (const float*)d_in[5];
  const float* sd   = (const float*)d_in[6];

  char* ws = (char*)d_ws;
  size_t o = 0;
  auto alloc = [&](size_t bytes) {
    char* p = ws + o;
    o += (bytes + 255) & ~(size_t)255;
    return (void*)p;
  };
  __bf16* xb     = (__bf16*)alloc((size_t)T_TOK * H_DIM * 2);
  __bf16* wgub   = (__bf16*)alloc((size_t)E_EXP * 2 * F_DIM * H_DIM * 2);
  __bf16* wdb    = (__bf16*)alloc((size_t)E_EXP * H_DIM * F_DIM * 2);
  __bf16* sgub   = (__bf16*)alloc((size_t)2 * FS_DIM * H_DIM * 2);
  __bf16* sdb    = (__bf16*)alloc((size_t)H_DIM * FS_DIM * 2);
  __bf16* h_buf  = (__bf16*)alloc((size_t)T_TOK * K_TOP * F_DIM * 2);
  float*  y_slot = (float*) alloc((size_t)T_TOK * K_TOP * H_DIM * 4);
  __bf16* hs     = (__bf16*)alloc((size_t)T_TOK * FS_DIM * 2);
  int*   tk_idx  = (int*)  alloc((size_t)T_TOK * K_TOP * 4);
  float* tk_w    = (float*)alloc((size_t)T_TOK * K_TOP * 4);
  int*   counts  = (int*)  alloc((size_t)E_EXP * 4);
  int*   recs    = (int*)  alloc((size_t)E_EXP * CAP * 4);
  if (o > ws_size) return;

  // 1. prep: route + xb conversion (blocks 0..511) ∥ wgu/sgu conversion (blocks 512..2047)
  hipMemsetAsync(counts, 0, E_EXP * 4, stream);
  prep_kernel<<<2048, 256, 0, stream>>>(x, gw, bias, tk_idx, tk_w, xb, wgu, wgub, sgu, sgub);

  // 2. scatter (wave-parallel atomics)
  scatter_kernel<<<(T_TOK * K_TOP + 255) / 256, 256, 0, stream>>>(tk_idx, counts, recs);

  // 3. gate_up (routed z<32, shared z=32,33, cvt wd+sd z=34)
  gemm_fused<0><<<dim3(F_DIM / 64, T_TOK / BM, E_EXP + 3), 256, 0, stream>>>(
      xb, xb, wgub, sgub, h_buf, hs, recs, counts, tk_w, wd, wdb, sd, sdb);

  // 4. down (routed z<32, shared z=32)
  gemm_fused<1><<<dim3(H_DIM / BN, T_TOK / BM, E_EXP + 1), 256, 0, stream>>>(
      h_buf, hs, wdb, sdb, y_slot, d_out, recs, counts, tk_w,
      (const float*)nullptr, (__bf16*)nullptr, (const float*)nullptr, (__bf16*)nullptr);

  // 5. combine
  combine_kernel<<<T_TOK * H_DIM / 4 / 256, 256, 0, stream>>>(y_slot, (float*)d_out);
}

// Round 11
// 302.720 us; speedup vs baseline: 4.2010x; 1.0967x over previous
//
#include <hip/hip_runtime.h>
#include <hip/hip_bf16.h>

#define T_TOK 2048
#define H_DIM 1024
#define E_EXP 32
#define F_DIM 512
#define FS_DIM 1024
#define K_TOP 8
#define NGRP 8
#define TGRP 4
#define GSZ (E_EXP / NGRP)
#define RSCALE 2.5f
#define CAP 2048

typedef short  short8 __attribute__((ext_vector_type(8)));
typedef __bf16 bf16x4 __attribute__((ext_vector_type(4)));
typedef float  f32x4  __attribute__((ext_vector_type(4)));

// ================ prep: route (blocks 0..511, wave-per-token) ∥ cvt ALL weights ================
// route and the weight conversions are data-independent; the route blocks' 18 us
// latency-bound work hides inside the ~321-MB HBM-bound conversion (R10: mechanism
// verified). NO atomics in route (R5 lesson: dependent per-wave atomicAdd -> 165 us).
// NO ride-along cvt inside GEMM dispatches (R10 lesson: extends the dispatch ~1:1).
#define NROUTE_BLK (T_TOK / 4)
__global__ __launch_bounds__(256) void prep_kernel(
    const float* __restrict__ x, const float* __restrict__ gw,
    const float* __restrict__ bias, int* __restrict__ tk_idx,
    float* __restrict__ tk_w, __bf16* __restrict__ xb,
    const float* __restrict__ s0, __bf16* __restrict__ d0, int n0,   // wgu
    const float* __restrict__ s1, __bf16* __restrict__ d1, int n1,   // wd
    const float* __restrict__ s2, __bf16* __restrict__ d2, int n2,   // sgu
    const float* __restrict__ s3, __bf16* __restrict__ d3, int n3) { // sd
  if (blockIdx.x < NROUTE_BLK) {
    const int wid = threadIdx.x >> 6, lane = threadIdx.x & 63;
    const int t = blockIdx.x * 4 + wid;
    float xr[16];
#pragma unroll
    for (int i = 0; i < 16; i++) xr[i] = x[t * H_DIM + i * 64 + lane];
#pragma unroll
    for (int i = 0; i < 16; i++) xb[t * H_DIM + i * 64 + lane] = (__bf16)xr[i];
    float sc[E_EXP];
#pragma unroll
    for (int e = 0; e < E_EXP; e++) {
      const float* w = gw + e * H_DIM;
      float s = 0.f;
#pragma unroll
      for (int i = 0; i < 16; i++) s += xr[i] * w[i * 64 + lane];
#pragma unroll
      for (int off = 32; off > 0; off >>= 1) s += __shfl_xor(s, off);
      sc[e] = 1.f / (1.f + expf(-s));
    }
    if (lane == 0) {
      float b[E_EXP];
      for (int e = 0; e < E_EXP; e++) b[e] = sc[e] + bias[e];
      float gs[NGRP];
      for (int g = 0; g < NGRP; g++) {
        float m1 = -1e30f, m2 = -1e30f;
        for (int j = 0; j < GSZ; j++) {
          float v = b[g * GSZ + j];
          if (v > m1) { m2 = m1; m1 = v; } else if (v > m2) { m2 = v; }
        }
        gs[g] = m1 + m2;
      }
      unsigned gmask = 0;
      for (int it = 0; it < TGRP; it++) {
        float best = -1e30f; int bi = 0;
        for (int g = 0; g < NGRP; g++)
          if (!((gmask >> g) & 1) && gs[g] > best) { best = gs[g]; bi = g; }
        gmask |= 1u << bi;
      }
      unsigned emask = 0; float wsum = 0.f;
      int idx8[K_TOP];
      for (int it = 0; it < K_TOP; it++) {
        float best = -1e30f; int bi = 0;
        for (int e = 0; e < E_EXP; e++) {
          if (!((gmask >> (e / GSZ)) & 1)) continue;
          if ((emask >> e) & 1) continue;
          if (b[e] > best) { best = b[e]; bi = e; }
        }
        emask |= 1u << bi;
        idx8[it] = bi;
        wsum += sc[bi];
      }
      const float inv = 1.f / (wsum + 1e-20f);
      for (int k = 0; k < K_TOP; k++) {
        tk_idx[t * K_TOP + k] = idx8[k];
        tk_w[t * K_TOP + k] = sc[idx8[k]] * inv;
      }
    }
  } else {
    // R6-proven cvt_all body over all four weight tensors
    const int ntot = n0 + n1 + n2 + n3;
    const int nthr = (gridDim.x - NROUTE_BLK) * 256;
    int gid = (blockIdx.x - NROUTE_BLK) * 256 + threadIdx.x;
    for (; gid < ntot; gid += nthr) {
      int i = gid;
      const float* src; __bf16* dst;
      if (i < n0) { src = s0; dst = d0; }
      else { i -= n0;
        if (i < n1) { src = s1; dst = d1; }
        else { i -= n1;
          if (i < n2) { src = s2; dst = d2; }
          else { i -= n2; src = s3; dst = d3; }
        }
      }
      const float4 v = reinterpret_cast<const float4*>(src)[i];
      bf16x4 o;
      o[0] = (__bf16)v.x; o[1] = (__bf16)v.y; o[2] = (__bf16)v.z; o[3] = (__bf16)v.w;
      reinterpret_cast<bf16x4*>(dst)[i] = o;
    }
  }
}

// ---------------- scatter: wave-parallel per-lane atomics ----------------
__global__ void scatter_kernel(const int* __restrict__ tk_idx, int* __restrict__ counts,
                               int* __restrict__ recs) {
  const int i = blockIdx.x * blockDim.x + threadIdx.x;
  if (i >= T_TOK * K_TOP) return;
  const int e = tk_idx[i];
  const int pos = atomicAdd(&counts[e], 1);
  recs[e * CAP + pos] = i;  // i == t*8 + k
}

// ---------------- fused grouped+shared GEMM (R6-proven m97 structure, 128x128, BK=64) ----------------
#define BM 128
#define BN 128
#define BK 64

__device__ __forceinline__ void gload_lds16(const void* g, void* l) {
  __builtin_amdgcn_global_load_lds(
      (__attribute__((address_space(1))) const void*)g,
      (__attribute__((address_space(3))) void*)l, 16, 0, 0);
}

// PHASE 0: z<32 -> GU expert z (A=xb gather, B=wgub, out=h_buf bf16 silu*up)
//          z in {32,33} -> shared GU slice s=z-32 (A=xb dense, B=sgub, out=hs)
// PHASE 1: z<32 -> DOWN expert z (A=h_buf slab, B=wdb, out=y_slot fp32 * tk_w)
//          z==32 -> shared DOWN (A=hs dense, B=sdb, out=d_out fp32)
template <int PHASE>
__global__ __launch_bounds__(256) void gemm_fused(
    const __bf16* __restrict__ Ar, const __bf16* __restrict__ As_,
    const __bf16* __restrict__ Br, const __bf16* __restrict__ Bs_,
    void* __restrict__ OutR, void* __restrict__ OutS,
    const int* __restrict__ recs, const int* __restrict__ counts,
    const float* __restrict__ tk_w) {

  const int z = blockIdx.z;
  const bool routed = (z < E_EXP);
  const int e = z;
  const int m0 = blockIdx.y * BM;
  const int bx = blockIdx.x;

  int count = T_TOK, off_e = 0;
  if (routed) {
    count = counts[e];
    for (int i = 0; i < E_EXP; i++) off_e += (i < e) ? counts[i] : 0;
    if (m0 >= count) return;   // block-uniform early exit, before any barrier
  }
  const int K = (PHASE == 0) ? H_DIM : (routed ? F_DIM : FS_DIM);

  const int tid = threadIdx.x, wid = tid >> 6, lane = tid & 63;

  __shared__ __align__(16) __bf16 Atile[BM * BK];
  __shared__ __align__(16) __bf16 Btile[BN * BK];

  const int colk = (lane & 7) * 8;
  const __bf16* aptr[4];
  const __bf16* bptr[4];
#pragma unroll
  for (int i = 0; i < 4; i++) {
    const int row = wid * 32 + i * 8 + (lane >> 3);
    int r = m0 + row; if (r > count - 1) r = count - 1;
    // ---- A source ----
    if (PHASE == 0) {
      if (routed) {
        const int rec = recs[e * CAP + r];
        aptr[i] = Ar + (size_t)(rec >> 3) * H_DIM + colk;     // gather token row of xb
      } else {
        aptr[i] = As_ + (size_t)r * H_DIM + colk;             // dense xb
      }
    } else {
      if (routed) aptr[i] = Ar + (size_t)(off_e + r) * F_DIM + colk;   // h slab
      else        aptr[i] = As_ + (size_t)r * FS_DIM + colk;           // hs dense
    }
    // ---- B source ----
    if (PHASE == 0) {
      if (routed) {
        const int brow = (row < 64) ? (bx * 64 + row) : (F_DIM + bx * 64 + row - 64);
        bptr[i] = Br + (size_t)e * 2 * F_DIM * H_DIM + (size_t)brow * H_DIM + colk;
      } else {
        const int s = z - E_EXP;
        const int fglob = s * 512 + bx * 64 + (row & 63);
        const int brow = (row < 64) ? fglob : (FS_DIM + fglob);
        bptr[i] = Bs_ + (size_t)brow * H_DIM + colk;
      }
    } else {
      if (routed) {
        const int brow = bx * BN + row;
        bptr[i] = Br + (size_t)e * H_DIM * F_DIM + (size_t)brow * F_DIM + colk;
      } else {
        const int brow = bx * BN + row;
        bptr[i] = Bs_ + (size_t)brow * FS_DIM + colk;
      }
    }
  }

  f32x4 acc[2][8];
#pragma unroll
  for (int a = 0; a < 2; a++)
#pragma unroll
    for (int b = 0; b < 8; b++) acc[a][b] = f32x4{0.f, 0.f, 0.f, 0.f};

  const int lr = lane & 15, lh = lane >> 4;

  for (int k0 = 0; k0 < K; k0 += BK) {
#pragma unroll
    for (int i = 0; i < 4; i++)
      gload_lds16(aptr[i] + k0, (char*)Atile + (wid * 4 + i) * 1024);
#pragma unroll
    for (int i = 0; i < 4; i++)
      gload_lds16(bptr[i] + k0, (char*)Btile + (wid * 4 + i) * 1024);
    __syncthreads();
#pragma unroll
    for (int kk = 0; kk < 2; kk++) {
      short8 af[2], bfr[8];
#pragma unroll
      for (int fm = 0; fm < 2; fm++)
        af[fm] = *reinterpret_cast<const short8*>(&Atile[(wid * 32 + fm * 16 + lr) * BK + kk * 32 + lh * 8]);
#pragma unroll
      for (int fn = 0; fn < 8; fn++)
        bfr[fn] = *reinterpret_cast<const short8*>(&Btile[(fn * 16 + lr) * BK + kk * 32 + lh * 8]);
#pragma unroll
      for (int fn = 0; fn < 8; fn++)
#pragma unroll
        for (int fm = 0; fm < 2; fm++)
          acc[fm][fn] = __builtin_amdgcn_mfma_f32_16x16x32_bf16(af[fm], bfr[fn], acc[fm][fn], 0, 0, 0);
    }
    __syncthreads();
  }

  // ---------------- epilogues ----------------
  if (PHASE == 0) {
    // silu(gate) * up -> bf16
#pragma unroll
    for (int fm = 0; fm < 2; fm++)
#pragma unroll
      for (int j = 0; j < 4; j++) {
        const int row = wid * 32 + fm * 16 + lh * 4 + j;
        if (m0 + row < count) {
#pragma unroll
          for (int fn = 0; fn < 4; fn++) {
            const float g = acc[fm][fn][j], u = acc[fm][fn + 4][j];
            const float hv = g / (1.f + expf(-g)) * u;
            if (routed) {
              const int f = bx * 64 + fn * 16 + lr;
              ((__bf16*)OutR)[(size_t)(off_e + m0 + row) * F_DIM + f] = (__bf16)hv;
            } else {
              const int s = z - E_EXP;
              const int f = s * 512 + bx * 64 + fn * 16 + lr;
              ((__bf16*)OutS)[(size_t)(m0 + row) * FS_DIM + f] = (__bf16)hv;
            }
          }
        }
      }
  } else {
#pragma unroll
    for (int fm = 0; fm < 2; fm++)
#pragma unroll
      for (int j = 0; j < 4; j++) {
        const int row = wid * 32 + fm * 16 + lh * 4 + j;
        if (m0 + row < count) {
          if (routed) {
            const int rec = recs[e * CAP + m0 + row];   // == t*8+k, the y_slot row
            const float w = tk_w[rec];
            const size_t base = (size_t)rec * H_DIM + bx * BN;
#pragma unroll
            for (int fn = 0; fn < 8; fn++)
              ((float*)OutR)[base + fn * 16 + lr] = acc[fm][fn][j] * w;
          } else {
#pragma unroll
            for (int fn = 0; fn < 8; fn++)
              ((float*)OutS)[(size_t)(m0 + row) * H_DIM + bx * BN + fn * 16 + lr] = acc[fm][fn][j];
          }
        }
      }
  }
}

// ---------------- combine: out = shared + SCALE * sum_k y_slot[t,k] ----------------
__global__ void combine_kernel(const float* __restrict__ y_slot, float* __restrict__ out) {
  const int gid = blockIdx.x * blockDim.x + threadIdx.x;
  const int t = gid >> 8;
  const int c0 = (gid & 255) * 4;
  float4 s = {0.f, 0.f, 0.f, 0.f};
#pragma unroll
  for (int k = 0; k < K_TOP; k++) {
    const float4 v = *reinterpret_cast<const float4*>(&y_slot[((size_t)t * K_TOP + k) * H_DIM + c0]);
    s.x += v.x; s.y += v.y; s.z += v.z; s.w += v.w;
  }
  float4 o = *reinterpret_cast<float4*>(&out[(size_t)t * H_DIM + c0]);
  o.x += RSCALE * s.x; o.y += RSCALE * s.y; o.z += RSCALE * s.z; o.w += RSCALE * s.w;
  *reinterpret_cast<float4*>(&out[(size_t)t * H_DIM + c0]) = o;
}

// ---------------- launch ----------------
extern "C" void kernel_launch(void* const* d_in, const int* in_sizes, int n_in,
                              void* d_out, int out_size, void* d_ws, size_t ws_size,
                              hipStream_t stream) {
  const float* x    = (const float*)d_in[0];
  const float* gw   = (const float*)d_in[1];
  const float* bias = (const float*)d_in[2];
  const float* wgu  = (const float*)d_in[3];
  const float* wd   = (const float*)d_in[4];
  const float* sgu  = (const float*)d_in[5];
  const float* sd   = (const float*)d_in[6];

  char* ws = (char*)d_ws;
  size_t o = 0;
  auto alloc = [&](size_t bytes) {
    char* p = ws + o;
    o += (bytes + 255) & ~(size_t)255;
    return (void*)p;
  };
  __bf16* xb     = (__bf16*)alloc((size_t)T_TOK * H_DIM * 2);
  __bf16* wgub   = (__bf16*)alloc((size_t)E_EXP * 2 * F_DIM * H_DIM * 2);
  __bf16* wdb    = (__bf16*)alloc((size_t)E_EXP * H_DIM * F_DIM * 2);
  __bf16* sgub   = (__bf16*)alloc((size_t)2 * FS_DIM * H_DIM * 2);
  __bf16* sdb    = (__bf16*)alloc((size_t)H_DIM * FS_DIM * 2);
  __bf16* h_buf  = (__bf16*)alloc((size_t)T_TOK * K_TOP * F_DIM * 2);
  float*  y_slot = (float*) alloc((size_t)T_TOK * K_TOP * H_DIM * 4);
  __bf16* hs     = (__bf16*)alloc((size_t)T_TOK * FS_DIM * 2);
  int*   tk_idx  = (int*)  alloc((size_t)T_TOK * K_TOP * 4);
  float* tk_w    = (float*)alloc((size_t)T_TOK * K_TOP * 4);
  int*   counts  = (int*)  alloc((size_t)E_EXP * 4);
  int*   recs    = (int*)  alloc((size_t)E_EXP * CAP * 4);
  if (o > ws_size) return;

  // 1. prep: route + xb (blocks 0..511) ∥ ALL weight conversions (blocks 512..2047)
  hipMemsetAsync(counts, 0, E_EXP * 4, stream);
  prep_kernel<<<2048, 256, 0, stream>>>(
      x, gw, bias, tk_idx, tk_w, xb,
      wgu, wgub, E_EXP * 2 * F_DIM * H_DIM / 4,
      wd,  wdb,  E_EXP * H_DIM * F_DIM / 4,
      sgu, sgub, 2 * FS_DIM * H_DIM / 4,
      sd,  sdb,  H_DIM * FS_DIM / 4);

  // 2. scatter (wave-parallel atomics)
  scatter_kernel<<<(T_TOK * K_TOP + 255) / 256, 256, 0, stream>>>(tk_idx, counts, recs);

  // 3. gate_up (routed z<32, shared slices z=32,33)
  gemm_fused<0><<<dim3(F_DIM / 64, T_TOK / BM, E_EXP + 2), 256, 0, stream>>>(
      xb, xb, wgub, sgub, h_buf, hs, recs, counts, tk_w);

  // 4. down (routed z<32, shared z=32)
  gemm_fused<1><<<dim3(H_DIM / BN, T_TOK / BM, E_EXP + 1), 256, 0, stream>>>(
      h_buf, hs, wdb, sdb, y_slot, d_out, recs, counts, tk_w);

  // 5. combine
  combine_kernel<<<T_TOK * H_DIM / 4 / 256, 256, 0, stream>>>(y_slot, (float*)d_out);
}